// Round 17
// baseline (297.783 us; speedup 1.0000x reference)
//
#include <hip/hip_runtime.h>
#include <hip/hip_bf16.h>
#include <stdint.h>

#define HIDDEN 1024
#define FFN    4096
#define NROWS  8192   // 4*2048
#define TOPK_K 32
#define NCAND  40
#define MU     3e-3f  // band >= 2.5x max fp16-approx error (1.2e-3)
#define KC     384    // OpenBLAS SGEMM_DEFAULT_Q (verified rounds 4-16)
#define CCAP   256    // candidate capacity (survivors ~125 +- 11; validated R5-R16)
#define T0     1.25f  // pre-filter threshold: 7.7 sigma below |h|_(40)

#define BM 128
#define BN 128
#define BK 32
#define NT (HIDDEN / BK)      // 32 K-tiles
#define BUFSZ (2 * BM * BK)   // f16 elems per ring slot (A+B) = 16 KB

typedef _Float16 f16;
typedef __attribute__((ext_vector_type(8))) _Float16 f16x8;
typedef __attribute__((ext_vector_type(4))) _Float16 f16x4;
typedef __attribute__((ext_vector_type(2))) _Float16 f16x2;
typedef __attribute__((ext_vector_type(4))) float f32x4;
typedef unsigned long long u64;
typedef unsigned int u32;

__device__ __forceinline__ void async_copy16(const void* g, void* l) {
  __builtin_amdgcn_global_load_lds((void __attribute__((address_space(1)))*)(g),
                                   (void __attribute__((address_space(3)))*)(l),
                                   16, 0, 0);
}

// ------------------------------------------------- fused preprocessing:
// blocks [0,2048): fp32->fp16 convert of x and W1 (grid-stride)
// blocks [2048,6144): W2 transpose tile -> f16 [4096][1024]
__global__ void prep_kernel(const float* __restrict__ x, const float* __restrict__ W1,
                            const float* __restrict__ W2,
                            f16* __restrict__ xh, f16* __restrict__ wh,
                            f16* __restrict__ w2t) {
  const int tid = threadIdx.x;
  if (blockIdx.x < 2048) {
    const int n4x = NROWS * HIDDEN / 4;
    const int n4w = FFN * HIDDEN / 4;
    int i = blockIdx.x * 256 + tid;
    int stride = 2048 * 256;
    for (; i < n4x + n4w; i += stride) {
      const float4 v = (i < n4x) ? reinterpret_cast<const float4*>(x)[i]
                                 : reinterpret_cast<const float4*>(W1)[i - n4x];
      f16x4 o = {(f16)v.x, (f16)v.y, (f16)v.z, (f16)v.w};
      if (i < n4x) reinterpret_cast<f16x4*>(xh)[i] = o;
      else         reinterpret_cast<f16x4*>(wh)[i - n4x] = o;
    }
  } else {
    __shared__ float tile[32][33];
    const int b = blockIdx.x - 2048;
    const int bx = (b & 127) * 32;          // FFN
    const int by = (b >> 7) * 32;           // HIDDEN
    const int tx = tid & 31, ty = tid >> 5; // 32 x 8
#pragma unroll
    for (int r = 0; r < 32; r += 8)
      tile[ty + r][tx] = W2[(size_t)(by + ty + r) * FFN + bx + tx];
    __syncthreads();
#pragma unroll
    for (int r = 0; r < 32; r += 8)
      w2t[(size_t)(bx + ty + r) * HIDDEN + by + tx] = (f16)tile[tx][ty + r];
  }
}

// ------------------------------------------------- GEMM1 + fused T0 filter
// R14 sync structure at HALF the LDS: 2-slot ring (32 KB -> 5 blocks/CU,
// 20 waves) with counted s_waitcnt vmcnt(4) + raw s_barrier. One variable
// changed vs R14/R16 (slots 3->2): tests whether occupancy (cross-block
// TLP) was the binding constraint. Chunk-swizzle unchanged (0 conflicts).
__global__ __launch_bounds__(256)
void gemm_topk_fused(const f16* __restrict__ xh,
                     const f16* __restrict__ wh,
                     const float* __restrict__ b1,
                     u64* __restrict__ ckeys, float* __restrict__ cvals,
                     int* __restrict__ cnt) {
  __shared__ __align__(16) f16 smem[2][BUFSZ];   // 32 KB

  const int tid = threadIdx.x;
  const int rowBase = blockIdx.x * BM;
  const int colBase = blockIdx.y * BN;

  const int wid = tid >> 6, lane = tid & 63;
  const int wr = (wid >> 1) * 64;       // wave row offset in tile
  const int wc = (wid & 1) * 64;        // wave col offset in tile
  const int lr = lane & 15;
  const int kch = lane >> 4;            // k-chunk 0..3 (8 f16 each)

  // staging: thread covers 16B; dest LDS = tid*16 bytes (linear, required)
  const int r0 = tid >> 2;              // 0..63
  const int r1 = r0 + 64;               // 64..127
  const int c = tid & 3;
  const int off0 = r0 * BK + c * 8;     // == tid*8 f16
  const int off1 = r1 * BK + c * 8;
  const int sw = (c ^ ((r0 >> 1) & 3)) * 8;   // inverse swizzle

  const size_t gA0 = (size_t)(rowBase + r0) * HIDDEN + sw;
  const size_t gA1 = (size_t)(rowBase + r1) * HIDDEN + sw;
  const size_t gB0 = (size_t)(colBase + r0) * HIDDEN + sw;
  const size_t gB1 = (size_t)(colBase + r1) * HIDDEN + sw;

  f32x4 acc[4][4];
  const f32x4 zero4 = {0.f, 0.f, 0.f, 0.f};
#pragma unroll
  for (int m = 0; m < 4; ++m)
#pragma unroll
    for (int n = 0; n < 4; ++n) acc[m][n] = zero4;

  // swizzled read offsets (row-dependent chunk XOR)
  int roffA[4], roffB[4];
#pragma unroll
  for (int m = 0; m < 4; ++m) {
    int row = wr + m * 16 + lr;
    roffA[m] = row * BK + ((kch ^ ((row >> 1) & 3)) << 3);
  }
#pragma unroll
  for (int n = 0; n < 4; ++n) {
    int row = wc + n * 16 + lr;
    roffB[n] = row * BK + ((kch ^ ((row >> 1) & 3)) << 3);
  }

#define STAGE(slot, kb)                                       \
  do {                                                        \
    f16* sA_ = smem[slot];                                    \
    f16* sB_ = smem[slot] + BM * BK;                          \
    async_copy16(xh + gA0 + (kb), sA_ + off0);                \
    async_copy16(xh + gA1 + (kb), sA_ + off1);                \
    async_copy16(wh + gB0 + (kb), sB_ + off0);                \
    async_copy16(wh + gB1 + (kb), sB_ + off1);                \
  } while (0)

#define COMPUTE(slot)                                         \
  do {                                                        \
    const f16* sA_ = smem[slot];                              \
    const f16* sB_ = smem[slot] + BM * BK;                    \
    f16x8 a[4], b[4];                                         \
    _Pragma("unroll")                                         \
    for (int m = 0; m < 4; ++m) a[m] = *(const f16x8*)(sA_ + roffA[m]); \
    _Pragma("unroll")                                         \
    for (int n = 0; n < 4; ++n) b[n] = *(const f16x8*)(sB_ + roffB[n]); \
    _Pragma("unroll")                                         \
    for (int m = 0; m < 4; ++m)                               \
      _Pragma("unroll")                                       \
      for (int n = 0; n < 4; ++n)                             \
        acc[m][n] = __builtin_amdgcn_mfma_f32_16x16x32_f16(a[m], b[n], acc[m][n], 0, 0, 0); \
  } while (0)

  // prologue: stage tile 0
  STAGE(0, 0);

  // main loop: stage t+1 (other slot), wait own stage t landed (vmcnt(4)
  // = stage(t+1)'s 4 loads may stay in flight), barrier aligns all waves.
  // Trailing barrier: all waves done reading slot t&1 before iter t+1
  // stages into (t+2)&1 == t&1.
  for (int t = 0; t < NT - 1; ++t) {
    STAGE((t + 1) & 1, (t + 1) * BK);
    asm volatile("s_waitcnt vmcnt(4)\n\ts_barrier" ::: "memory");
    COMPUTE(t & 1);
    asm volatile("s_barrier" ::: "memory");
  }
  asm volatile("s_waitcnt vmcnt(0)\n\ts_barrier" ::: "memory");
  COMPUTE((NT - 1) & 1);
#undef STAGE
#undef COMPUTE

  // epilogue: bias + T0 filter + compact append
  // C/D layout (verified m89/m91): col = lane&15, row = (lane>>4)*4 + reg
  const int ccol = lane & 15;
  const int crow = (lane >> 4) * 4;
#pragma unroll
  for (int n = 0; n < 4; ++n) {
    int col = colBase + wc + n * 16 + ccol;
    float bias = b1[col];
    u32 inv = 0xFFFFFFFFu - (u32)col;
#pragma unroll
    for (int m = 0; m < 4; ++m) {
      int rowb = rowBase + wr + m * 16 + crow;
#pragma unroll
      for (int j = 0; j < 4; ++j) {
        float val = acc[m][n][j] + bias;
        if (fabsf(val) >= T0) {
          int row = rowb + j;
          int pos = atomicAdd(&cnt[row], 1);
          if (pos < CCAP) {
            ckeys[(size_t)row * CCAP + pos] =
                ((u64)__float_as_uint(fabsf(val)) << 32) | (u64)inv;
            cvals[(size_t)row * CCAP + pos] = val;
          }
        }
      }
    }
  }
}

// ------------------------------------------------- per-row select + adjudicate
// Rank-select top-40, verified round-4..16 adjudication (MU-band classify,
// OpenBLAS kc=384 fp32-chain emulation, cube), index-ascending output.
__global__ __launch_bounds__(256)
void topk_select(const u64* __restrict__ ckeys, const float* __restrict__ cvals,
                 const int* __restrict__ cnt,
                 const float* __restrict__ x, const float* __restrict__ W1,
                 const float* __restrict__ b1,
                 int* __restrict__ tidx, float* __restrict__ tcoef) {
  const int row = blockIdx.x;
  const int tid = threadIdx.x;

  __shared__ u64 k_lds[CCAP];
  __shared__ float v_lds[CCAP];
  __shared__ float sval[NCAND];
  __shared__ int   sidx[NCAND];
  __shared__ int   sS, sB;
  __shared__ float sv32[NCAND];
  __shared__ int   fidx[TOPK_K];
  __shared__ float fcoef[TOPK_K];

  int c = cnt[row];
  c = c < CCAP ? c : CCAP;
  if (tid < c) {
    k_lds[tid] = ckeys[(size_t)row * CCAP + tid];
    v_lds[tid] = cvals[(size_t)row * CCAP + tid];
  }
  if (tid < NCAND) { sval[tid] = 0.f; sidx[tid] = 0x7FFF0000 + tid; }
  __syncthreads();

  // parallel rank-select (keys unique -> strict order)
  if (tid < c) {
    const u64 mine = k_lds[tid];
    int rank = 0;
    for (int j2 = 0; j2 < c; ++j2)
      rank += (k_lds[j2] > mine) ? 1 : 0;
    if (rank < NCAND) {
      sval[rank] = v_lds[tid];
      sidx[rank] = (int)(0xFFFFFFFFu - (u32)(mine & 0xFFFFFFFFull));
    }
  }
  __syncthreads();

  // classify: sure-in prefix (> t+MU) vs boundary band [t-MU, t+MU]
  if (tid == 0) {
    float t = fabsf(sval[TOPK_K - 1]);
    int s = 0;
    while (s < TOPK_K - 1 && fabsf(sval[s]) > t + MU) ++s;
    int e = s;
    while (e < NCAND && fabsf(sval[e]) >= t - MU) ++e;
    sS = s;
    sB = e - s;       // >= 1 always (slot 31 is in the band)
  }
  __syncthreads();
  const int s = sS, nb = sB;

  // OpenBLAS-sgemm rounding emulation for boundary candidates
  if (nb > 1 && tid < nb) {
    const int fi = sidx[s + tid];
    const float* xr = x + (size_t)row * HIDDEN;
    const float* w1r = W1 + (size_t)fi * HIDDEN;
    float p0 = 0.0f, p1 = 0.0f, p2 = 0.0f;
    for (int k2 = 0; k2 < KC; ++k2)
      p0 = __builtin_fmaf(xr[k2], w1r[k2], p0);
    for (int k2 = KC; k2 < 2 * KC; ++k2)
      p1 = __builtin_fmaf(xr[k2], w1r[k2], p1);
    for (int k2 = 2 * KC; k2 < HIDDEN; ++k2)
      p2 = __builtin_fmaf(xr[k2], w1r[k2], p2);
    float acc = __fadd_rn(__fadd_rn(p0, p1), p2);   // C += panel merges
    sv32[tid] = __fadd_rn(acc, b1[fi]);
  }
  __syncthreads();

  if (tid == 0) {
    for (int k2 = 0; k2 < TOPK_K; ++k2) {
      fidx[k2] = sidx[k2];
      float hv = sval[k2];
      fcoef[k2] = __fmul_rn(__fmul_rn(hv, hv), hv);
    }
    if (nb > 1) {
      int need = TOPK_K - s;
      u64 used = 0;
      for (int n = 0; n < need; ++n) {
        int bestc = -1;
        u64 bestk = 0;
        for (int c2 = 0; c2 < nb; ++c2) {
          if (used & (1ull << c2)) continue;
          unsigned abv = __float_as_uint(fabsf(sv32[c2]));
          u64 kk2 = ((u64)abv << 32) | (u64)(0xFFFFFFFFu - (unsigned)sidx[s + c2]);
          if (bestc < 0 || kk2 > bestk) { bestk = kk2; bestc = c2; }
        }
        used |= 1ull << bestc;
        float hv = sv32[bestc];
        fidx[s + n] = sidx[s + bestc];
        fcoef[s + n] = __fmul_rn(__fmul_rn(hv, hv), hv);
      }
    }
  }
  __syncthreads();

  // index-ascending placement (indices unique -> exact permutation)
  if (tid < TOPK_K) {
    int myi = fidx[tid];
    float myc = fcoef[tid];
    int rank = 0;
#pragma unroll
    for (int j2 = 0; j2 < TOPK_K; ++j2)
      rank += (fidx[j2] < myi) ? 1 : 0;
    tidx[(size_t)row * TOPK_K + rank] = myi;
    tcoef[(size_t)row * TOPK_K + rank] = myc;
  }
}

// ------------------------------------------------- gather: out = sum coef*W2T[idx] + b2
// Column-halved + phase-ordered (4 MB working set per phase).
__global__ __launch_bounds__(256)
void gather_kernel(const int* __restrict__ tidx, const float* __restrict__ tcoef,
                   const f16* __restrict__ w2t, const float* __restrict__ b2,
                   float* __restrict__ out) {
  const int bid = blockIdx.x;
  const int row = bid & (NROWS - 1);
  const int half = bid >> 13;            // 0 or 1
  const int tid = threadIdx.x;
  const int colBase = half * (HIDDEN / 2);
  const int col = colBase + tid * 2;     // 2 f16 per thread

  __shared__ int sIdx[TOPK_K];
  __shared__ float sCf[TOPK_K];
  if (tid < TOPK_K) {
    sIdx[tid] = tidx[(size_t)row * TOPK_K + tid];
    sCf[tid] = tcoef[(size_t)row * TOPK_K + tid];
  }
  __syncthreads();

  float ax = 0.f, ay = 0.f;
#pragma unroll
  for (int g = 0; g < TOPK_K; g += 8) {
    f16x2 w[8];
    float cf[8];
#pragma unroll
    for (int u = 0; u < 8; ++u) {
      w[u] = *reinterpret_cast<const f16x2*>(w2t + (size_t)sIdx[g + u] * HIDDEN + col);
      cf[u] = sCf[g + u];
    }
#pragma unroll
    for (int u = 0; u < 8; ++u) {
      ax = __builtin_fmaf(cf[u], (float)w[u][0], ax);
      ay = __builtin_fmaf(cf[u], (float)w[u][1], ay);
    }
  }
  float2 o;
  o.x = ax + b2[col];
  o.y = ay + b2[col + 1];
  reinterpret_cast<float2*>(out)[((size_t)row * HIDDEN + col) / 2] = o;
}

// ------------------------------------------------- launch
extern "C" void kernel_launch(void* const* d_in, const int* in_sizes, int n_in,
                              void* d_out, int out_size, void* d_ws, size_t ws_size,
                              hipStream_t stream) {
  (void)in_sizes; (void)n_in; (void)out_size; (void)ws_size;
  const float* x  = (const float*)d_in[0];
  const float* W1 = (const float*)d_in[1];
  const float* b1 = (const float*)d_in[2];
  const float* W2 = (const float*)d_in[3];
  const float* b2 = (const float*)d_in[4];
  float* out = (float*)d_out;

  // workspace layout (~61 MB total)
  f16* xh = (f16*)d_ws;                                           // 16.78 MB
  f16* wh = xh + (size_t)NROWS * HIDDEN;                          //  8.39 MB
  f16* w2t = wh + (size_t)FFN * HIDDEN;                           //  8.39 MB
  u64* ckeys = (u64*)(w2t + (size_t)FFN * HIDDEN);                // 16.78 MB
  float* cvals = (float*)(ckeys + (size_t)NROWS * CCAP);          //  8.39 MB
  int* cnt = (int*)(cvals + (size_t)NROWS * CCAP);                //  32 KB
  int* tidx = cnt + NROWS;                                        //  1.05 MB
  float* tcoef = (float*)(tidx + (size_t)NROWS * TOPK_K);         //  1.05 MB

  hipMemsetAsync(cnt, 0, NROWS * sizeof(int), stream);
  prep_kernel<<<6144, 256, 0, stream>>>(x, W1, W2, xh, wh, w2t);
  gemm_topk_fused<<<dim3(NROWS / BM, FFN / BN), 256, 0, stream>>>(xh, wh, b1, ckeys, cvals, cnt);
  topk_select<<<NROWS, 256, 0, stream>>>(ckeys, cvals, cnt, x, W1, b1, tidx, tcoef);
  gather_kernel<<<2 * NROWS, 256, 0, stream>>>(tidx, tcoef, w2t, b2, out);
}

// Round 18
// 286.812 us; speedup vs baseline: 1.0383x; 1.0383x over previous
//
#include <hip/hip_runtime.h>
#include <hip/hip_bf16.h>
#include <stdint.h>

#define HIDDEN 1024
#define FFN    4096
#define NROWS  8192   // 4*2048
#define TOPK_K 32
#define NCAND  40
#define MU     3e-3f  // band >= 2.5x max fp16-approx error (1.2e-3)
#define KC     384    // OpenBLAS SGEMM_DEFAULT_Q (verified rounds 4-17)
#define CCAP   256    // candidate capacity (survivors ~125 +- 11; validated R5-R17)
#define T0     1.25f  // pre-filter threshold: 7.7 sigma below |h|_(40)

#define BM 128
#define BN 128
#define BK 32
#define NT (HIDDEN / BK)      // 32 K-tiles
#define BUFSZ (2 * BM * BK)   // f16 elems per ring slot (A+B) = 16 KB

typedef _Float16 f16;
typedef __attribute__((ext_vector_type(8))) _Float16 f16x8;
typedef __attribute__((ext_vector_type(4))) _Float16 f16x4;
typedef __attribute__((ext_vector_type(4))) float f32x4;
typedef unsigned long long u64;
typedef unsigned int u32;

__device__ __forceinline__ void async_copy16(const void* g, void* l) {
  __builtin_amdgcn_global_load_lds((void __attribute__((address_space(1)))*)(g),
                                   (void __attribute__((address_space(3)))*)(l),
                                   16, 0, 0);
}

// ------------------------------------------------- fused preprocessing:
// blocks [0,2048): fp32->fp16 convert of x and W1 (grid-stride) + zero cnt
// blocks [2048,6144): W2 transpose tile -> f16 [4096][1024]
__global__ void prep_kernel(const float* __restrict__ x, const float* __restrict__ W1,
                            const float* __restrict__ W2,
                            f16* __restrict__ xh, f16* __restrict__ wh,
                            f16* __restrict__ w2t, int* __restrict__ cnt) {
  const int tid = threadIdx.x;
  if (blockIdx.x < 2048) {
    if (tid < 4) cnt[blockIdx.x * 4 + tid] = 0;   // 2048*4 = 8192 entries
    const int n4x = NROWS * HIDDEN / 4;
    const int n4w = FFN * HIDDEN / 4;
    int i = blockIdx.x * 256 + tid;
    int stride = 2048 * 256;
    for (; i < n4x + n4w; i += stride) {
      const float4 v = (i < n4x) ? reinterpret_cast<const float4*>(x)[i]
                                 : reinterpret_cast<const float4*>(W1)[i - n4x];
      f16x4 o = {(f16)v.x, (f16)v.y, (f16)v.z, (f16)v.w};
      if (i < n4x) reinterpret_cast<f16x4*>(xh)[i] = o;
      else         reinterpret_cast<f16x4*>(wh)[i - n4x] = o;
    }
  } else {
    __shared__ float tile[32][33];
    const int b = blockIdx.x - 2048;
    const int bx = (b & 127) * 32;          // FFN
    const int by = (b >> 7) * 32;           // HIDDEN
    const int tx = tid & 31, ty = tid >> 5; // 32 x 8
#pragma unroll
    for (int r = 0; r < 32; r += 8)
      tile[ty + r][tx] = W2[(size_t)(by + ty + r) * FFN + bx + tx];
    __syncthreads();
#pragma unroll
    for (int r = 0; r < 32; r += 8)
      w2t[(size_t)(bx + ty + r) * HIDDEN + by + tx] = (f16)tile[tx][ty + r];
  }
}

// ------------------------------------------------- GEMM1 + fused T0 filter
// Best measured across 8 structures (157-163 us): fp16 single-product,
// 128x128 tile, BK=32, 3-slot LDS ring (A+B, 48 KB) with counted
// s_waitcnt vmcnt(8) + raw s_barrier (stage t+2 while computing t -> 2
// iterations of load slack). LDS chunk-swizzle (rule #21 both-sides,
// verified 0 conflicts R9-R17). No setprio / XCD swizzle (measured null
// or harmful here).
__global__ __launch_bounds__(256)
void gemm_topk_fused(const f16* __restrict__ xh,
                     const f16* __restrict__ wh,
                     const float* __restrict__ b1,
                     u64* __restrict__ ckeys, float* __restrict__ cvals,
                     int* __restrict__ cnt) {
  __shared__ __align__(16) f16 smem[3][BUFSZ];   // 48 KB

  const int tid = threadIdx.x;
  const int rowBase = blockIdx.x * BM;
  const int colBase = blockIdx.y * BN;

  const int wid = tid >> 6, lane = tid & 63;
  const int wr = (wid >> 1) * 64;       // wave row offset in tile
  const int wc = (wid & 1) * 64;        // wave col offset in tile
  const int lr = lane & 15;
  const int kch = lane >> 4;            // k-chunk 0..3 (8 f16 each)

  // staging: thread covers 16B; dest LDS = tid*16 bytes (linear, required)
  const int r0 = tid >> 2;              // 0..63
  const int r1 = r0 + 64;               // 64..127
  const int c = tid & 3;
  const int off0 = r0 * BK + c * 8;     // == tid*8 f16
  const int off1 = r1 * BK + c * 8;
  const int sw = (c ^ ((r0 >> 1) & 3)) * 8;   // inverse swizzle

  const size_t gA0 = (size_t)(rowBase + r0) * HIDDEN + sw;
  const size_t gA1 = (size_t)(rowBase + r1) * HIDDEN + sw;
  const size_t gB0 = (size_t)(colBase + r0) * HIDDEN + sw;
  const size_t gB1 = (size_t)(colBase + r1) * HIDDEN + sw;

  f32x4 acc[4][4];
  const f32x4 zero4 = {0.f, 0.f, 0.f, 0.f};
#pragma unroll
  for (int m = 0; m < 4; ++m)
#pragma unroll
    for (int n = 0; n < 4; ++n) acc[m][n] = zero4;

  // swizzled read offsets (row-dependent chunk XOR)
  int roffA[4], roffB[4];
#pragma unroll
  for (int m = 0; m < 4; ++m) {
    int row = wr + m * 16 + lr;
    roffA[m] = row * BK + ((kch ^ ((row >> 1) & 3)) << 3);
  }
#pragma unroll
  for (int n = 0; n < 4; ++n) {
    int row = wc + n * 16 + lr;
    roffB[n] = row * BK + ((kch ^ ((row >> 1) & 3)) << 3);
  }

#define STAGE(slot, kb)                                       \
  do {                                                        \
    f16* sA_ = smem[slot];                                    \
    f16* sB_ = smem[slot] + BM * BK;                          \
    async_copy16(xh + gA0 + (kb), sA_ + off0);                \
    async_copy16(xh + gA1 + (kb), sA_ + off1);                \
    async_copy16(wh + gB0 + (kb), sB_ + off0);                \
    async_copy16(wh + gB1 + (kb), sB_ + off1);                \
  } while (0)

#define COMPUTE(slot)                                         \
  do {                                                        \
    const f16* sA_ = smem[slot];                              \
    const f16* sB_ = smem[slot] + BM * BK;                    \
    f16x8 a[4], b[4];                                         \
    _Pragma("unroll")                                         \
    for (int m = 0; m < 4; ++m) a[m] = *(const f16x8*)(sA_ + roffA[m]); \
    _Pragma("unroll")                                         \
    for (int n = 0; n < 4; ++n) b[n] = *(const f16x8*)(sB_ + roffB[n]); \
    _Pragma("unroll")                                         \
    for (int m = 0; m < 4; ++m)                               \
      _Pragma("unroll")                                       \
      for (int n = 0; n < 4; ++n)                             \
        acc[m][n] = __builtin_amdgcn_mfma_f32_16x16x32_f16(a[m], b[n], acc[m][n], 0, 0, 0); \
  } while (0)

  // prologue: stage tiles 0 and 1
  STAGE(0, 0);
  STAGE(1, BK);

  for (int t = 0; t < NT - 2; ++t) {
    STAGE((t + 2) % 3, (t + 2) * BK);
    asm volatile("s_waitcnt vmcnt(8)\n\ts_barrier" ::: "memory");
    COMPUTE(t % 3);
    asm volatile("s_barrier" ::: "memory");   // protect slot (t-1)%3 reuse
  }
  asm volatile("s_waitcnt vmcnt(4)\n\ts_barrier" ::: "memory");
  COMPUTE((NT - 2) % 3);
  asm volatile("s_barrier" ::: "memory");
  asm volatile("s_waitcnt vmcnt(0)\n\ts_barrier" ::: "memory");
  COMPUTE((NT - 1) % 3);
#undef STAGE
#undef COMPUTE

  // epilogue: bias + T0 filter + compact append
  // C/D layout (verified m89/m91): col = lane&15, row = (lane>>4)*4 + reg
  const int ccol = lane & 15;
  const int crow = (lane >> 4) * 4;
#pragma unroll
  for (int n = 0; n < 4; ++n) {
    int col = colBase + wc + n * 16 + ccol;
    float bias = b1[col];
    u32 inv = 0xFFFFFFFFu - (u32)col;
#pragma unroll
    for (int m = 0; m < 4; ++m) {
      int rowb = rowBase + wr + m * 16 + crow;
#pragma unroll
      for (int j = 0; j < 4; ++j) {
        float val = acc[m][n][j] + bias;
        if (fabsf(val) >= T0) {
          int row = rowb + j;
          int pos = atomicAdd(&cnt[row], 1);
          if (pos < CCAP) {
            ckeys[(size_t)row * CCAP + pos] =
                ((u64)__float_as_uint(fabsf(val)) << 32) | (u64)inv;
            cvals[(size_t)row * CCAP + pos] = val;
          }
        }
      }
    }
  }
}

// ------------------------------------------------- per-row select + adjudicate + gather (fused)
// Rank-select top-40, verified round-4..17 adjudication (MU-band classify,
// OpenBLAS kc=384 fp32-chain emulation, cube), index-ascending order, then
// the sparse gather from fp16 W2T.
__global__ __launch_bounds__(256)
void topk_scatter(const u64* __restrict__ ckeys, const float* __restrict__ cvals,
                  const int* __restrict__ cnt,
                  const float* __restrict__ x, const float* __restrict__ W1,
                  const float* __restrict__ b1,
                  const f16* __restrict__ w2t, const float* __restrict__ b2,
                  float* __restrict__ out) {
  const int row = blockIdx.x;
  const int tid = threadIdx.x;

  __shared__ u64 k_lds[CCAP];
  __shared__ float v_lds[CCAP];
  __shared__ float sval[NCAND];
  __shared__ int   sidx[NCAND];
  __shared__ int   sS, sB;
  __shared__ float sv32[NCAND];
  __shared__ int   fidx[TOPK_K];
  __shared__ float fcoef[TOPK_K];
  __shared__ int   sIdx[TOPK_K];     // index-ascending
  __shared__ float sCf[TOPK_K];

  int c = cnt[row];
  c = c < CCAP ? c : CCAP;
  if (tid < c) {
    k_lds[tid] = ckeys[(size_t)row * CCAP + tid];
    v_lds[tid] = cvals[(size_t)row * CCAP + tid];
  }
  if (tid < NCAND) { sval[tid] = 0.f; sidx[tid] = 0x7FFF0000 + tid; }
  __syncthreads();

  // parallel rank-select (keys unique -> strict order)
  if (tid < c) {
    const u64 mine = k_lds[tid];
    int rank = 0;
    for (int j2 = 0; j2 < c; ++j2)
      rank += (k_lds[j2] > mine) ? 1 : 0;
    if (rank < NCAND) {
      sval[rank] = v_lds[tid];
      sidx[rank] = (int)(0xFFFFFFFFu - (u32)(mine & 0xFFFFFFFFull));
    }
  }
  __syncthreads();

  // classify: sure-in prefix (> t+MU) vs boundary band [t-MU, t+MU]
  if (tid == 0) {
    float t = fabsf(sval[TOPK_K - 1]);
    int s = 0;
    while (s < TOPK_K - 1 && fabsf(sval[s]) > t + MU) ++s;
    int e = s;
    while (e < NCAND && fabsf(sval[e]) >= t - MU) ++e;
    sS = s;
    sB = e - s;       // >= 1 always (slot 31 is in the band)
  }
  __syncthreads();
  const int s = sS, nb = sB;

  // OpenBLAS-sgemm rounding emulation for boundary candidates
  if (nb > 1 && tid < nb) {
    const int fi = sidx[s + tid];
    const float* xr = x + (size_t)row * HIDDEN;
    const float* w1r = W1 + (size_t)fi * HIDDEN;
    float p0 = 0.0f, p1 = 0.0f, p2 = 0.0f;
    for (int k2 = 0; k2 < KC; ++k2)
      p0 = __builtin_fmaf(xr[k2], w1r[k2], p0);
    for (int k2 = KC; k2 < 2 * KC; ++k2)
      p1 = __builtin_fmaf(xr[k2], w1r[k2], p1);
    for (int k2 = 2 * KC; k2 < HIDDEN; ++k2)
      p2 = __builtin_fmaf(xr[k2], w1r[k2], p2);
    float acc = __fadd_rn(__fadd_rn(p0, p1), p2);   // C += panel merges
    sv32[tid] = __fadd_rn(acc, b1[fi]);
  }
  __syncthreads();

  if (tid == 0) {
    for (int k2 = 0; k2 < TOPK_K; ++k2) {
      fidx[k2] = sidx[k2];
      float hv = sval[k2];
      fcoef[k2] = __fmul_rn(__fmul_rn(hv, hv), hv);
    }
    if (nb > 1) {
      int need = TOPK_K - s;
      u64 used = 0;
      for (int n = 0; n < need; ++n) {
        int bestc = -1;
        u64 bestk = 0;
        for (int c2 = 0; c2 < nb; ++c2) {
          if (used & (1ull << c2)) continue;
          unsigned abv = __float_as_uint(fabsf(sv32[c2]));
          u64 kk2 = ((u64)abv << 32) | (u64)(0xFFFFFFFFu - (unsigned)sidx[s + c2]);
          if (bestc < 0 || kk2 > bestk) { bestk = kk2; bestc = c2; }
        }
        used |= 1ull << bestc;
        float hv = sv32[bestc];
        fidx[s + n] = sidx[s + bestc];
        fcoef[s + n] = __fmul_rn(__fmul_rn(hv, hv), hv);
      }
    }
  }
  __syncthreads();

  // index-ascending placement into LDS (indices unique -> exact permutation)
  if (tid < TOPK_K) {
    int myi = fidx[tid];
    float myc = fcoef[tid];
    int rank = 0;
#pragma unroll
    for (int j2 = 0; j2 < TOPK_K; ++j2)
      rank += (fidx[j2] < myi) ? 1 : 0;
    sIdx[rank] = myi;
    sCf[rank] = myc;
  }
  __syncthreads();

  // sparse gather from fp16 W2T: out[row][:] = sum_j coef_j * W2T[idx_j][:] + b2
  float4 acc = {0.f, 0.f, 0.f, 0.f};
  for (int j = 0; j < TOPK_K; ++j) {
    const f16x4 w = *reinterpret_cast<const f16x4*>(w2t + (size_t)sIdx[j] * HIDDEN + tid * 4);
    float cf = sCf[j];
    acc.x = __builtin_fmaf(cf, (float)w[0], acc.x);
    acc.y = __builtin_fmaf(cf, (float)w[1], acc.y);
    acc.z = __builtin_fmaf(cf, (float)w[2], acc.z);
    acc.w = __builtin_fmaf(cf, (float)w[3], acc.w);
  }
  const float4 bb = reinterpret_cast<const float4*>(b2)[tid];
  acc.x += bb.x; acc.y += bb.y; acc.z += bb.z; acc.w += bb.w;
  reinterpret_cast<float4*>(out)[(size_t)row * (HIDDEN / 4) + tid] = acc;
}

// ------------------------------------------------- launch
extern "C" void kernel_launch(void* const* d_in, const int* in_sizes, int n_in,
                              void* d_out, int out_size, void* d_ws, size_t ws_size,
                              hipStream_t stream) {
  (void)in_sizes; (void)n_in; (void)out_size; (void)ws_size;
  const float* x  = (const float*)d_in[0];
  const float* W1 = (const float*)d_in[1];
  const float* b1 = (const float*)d_in[2];
  const float* W2 = (const float*)d_in[3];
  const float* b2 = (const float*)d_in[4];
  float* out = (float*)d_out;

  // workspace layout (~59 MB total)
  f16* xh = (f16*)d_ws;                                           // 16.78 MB
  f16* wh = xh + (size_t)NROWS * HIDDEN;                          //  8.39 MB
  f16* w2t = wh + (size_t)FFN * HIDDEN;                           //  8.39 MB
  u64* ckeys = (u64*)(w2t + (size_t)FFN * HIDDEN);                // 16.78 MB
  float* cvals = (float*)(ckeys + (size_t)NROWS * CCAP);          //  8.39 MB
  int* cnt = (int*)(cvals + (size_t)NROWS * CCAP);                //  32 KB

  prep_kernel<<<6144, 256, 0, stream>>>(x, W1, W2, xh, wh, w2t, cnt);
  gemm_topk_fused<<<dim3(NROWS / BM, FFN / BN), 256, 0, stream>>>(xh, wh, b1, ckeys, cvals, cnt);
  topk_scatter<<<NROWS, 256, 0, stream>>>(ckeys, cvals, cnt, x, W1, b1, w2t, b2, out);
}

// Round 19
// 265.357 us; speedup vs baseline: 1.1222x; 1.0809x over previous
//
#include <hip/hip_runtime.h>
#include <hip/hip_bf16.h>
#include <stdint.h>

#define HIDDEN 1024
#define FFN    4096
#define NROWS  8192   // 4*2048
#define TOPK_K 32
#define NCAND  40
#define MU     3e-3f  // band >= 2.5x max fp16-approx error (1.2e-3)
#define KC     384    // OpenBLAS SGEMM_DEFAULT_Q (verified rounds 4-18)
#define CCAP   256    // candidate capacity (survivors ~125 +- 11; validated R5-R18)
#define T0     1.25f  // pre-filter threshold: 7.7 sigma below |h|_(40)

#define BM 256
#define BN 128
#define BK 32
#define NT (HIDDEN / BK)        // 32 K-tiles
#define BUFSZ ((BM + BN) * BK)  // f16 elems per ring slot (A+B) = 24 KB

typedef _Float16 f16;
typedef __attribute__((ext_vector_type(8))) _Float16 f16x8;
typedef __attribute__((ext_vector_type(4))) _Float16 f16x4;
typedef __attribute__((ext_vector_type(4))) float f32x4;
typedef unsigned long long u64;
typedef unsigned int u32;

__device__ __forceinline__ void async_copy16(const void* g, void* l) {
  __builtin_amdgcn_global_load_lds((void __attribute__((address_space(1)))*)(g),
                                   (void __attribute__((address_space(3)))*)(l),
                                   16, 0, 0);
}

// ------------------------------------------------- fused preprocessing:
// blocks [0,2048): fp32->fp16 convert of x and W1 (grid-stride) + zero cnt
// blocks [2048,6144): W2 transpose tile -> f16 [4096][1024]
__global__ void prep_kernel(const float* __restrict__ x, const float* __restrict__ W1,
                            const float* __restrict__ W2,
                            f16* __restrict__ xh, f16* __restrict__ wh,
                            f16* __restrict__ w2t, int* __restrict__ cnt) {
  const int tid = threadIdx.x;
  if (blockIdx.x < 2048) {
    if (tid < 4) cnt[blockIdx.x * 4 + tid] = 0;   // 2048*4 = 8192 entries
    const int n4x = NROWS * HIDDEN / 4;
    const int n4w = FFN * HIDDEN / 4;
    int i = blockIdx.x * 256 + tid;
    int stride = 2048 * 256;
    for (; i < n4x + n4w; i += stride) {
      const float4 v = (i < n4x) ? reinterpret_cast<const float4*>(x)[i]
                                 : reinterpret_cast<const float4*>(W1)[i - n4x];
      f16x4 o = {(f16)v.x, (f16)v.y, (f16)v.z, (f16)v.w};
      if (i < n4x) reinterpret_cast<f16x4*>(xh)[i] = o;
      else         reinterpret_cast<f16x4*>(wh)[i - n4x] = o;
    }
  } else {
    __shared__ float tile[32][33];
    const int b = blockIdx.x - 2048;
    const int bx = (b & 127) * 32;          // FFN
    const int by = (b >> 7) * 32;           // HIDDEN
    const int tx = tid & 31, ty = tid >> 5; // 32 x 8
#pragma unroll
    for (int r = 0; r < 32; r += 8)
      tile[ty + r][tx] = W2[(size_t)(by + ty + r) * FFN + bx + tx];
    __syncthreads();
#pragma unroll
    for (int r = 0; r < 32; r += 8)
      w2t[(size_t)(bx + ty + r) * HIDDEN + by + tx] = (f16)tile[tx][ty + r];
  }
}

// ------------------------------------------------- GEMM1 + fused T0 filter
// Untried tile-space corner: 256x128 / 8 waves (64x64 per wave), 3-slot
// ring (72 KB -> 2 blocks/CU = 16 waves/CU, 2x R14's resident waves) with
// counted s_waitcnt vmcnt(6) + raw s_barrier. Arithmetic intensity +33%
// vs 128^2 (87 vs 65 FLOP per staged LDS byte). Chunk-swizzle unchanged
// (rule #21 both-sides, 0 conflicts R9-R18; swizzle class invariant under
// row+128 since 128 is a multiple of 8).
__global__ __launch_bounds__(512)
void gemm_topk_fused(const f16* __restrict__ xh,
                     const f16* __restrict__ wh,
                     const float* __restrict__ b1,
                     u64* __restrict__ ckeys, float* __restrict__ cvals,
                     int* __restrict__ cnt) {
  __shared__ __align__(16) f16 smem[3][BUFSZ];   // 72 KB

  const int tid = threadIdx.x;
  const int rowBase = blockIdx.x * BM;
  const int colBase = blockIdx.y * BN;

  const int wid = tid >> 6, lane = tid & 63;
  const int wr = (wid >> 1) * 64;       // wave row offset (0..192)
  const int wc = (wid & 1) * 64;        // wave col offset (0 or 64)
  const int lr = lane & 15;
  const int kch = lane >> 4;            // k-chunk 0..3 (8 f16 each)

  // staging: 512 threads; A = 2 instr (rows 0..127, 128..255), B = 1 instr
  // (rows 0..127). Chunk idx i*512+tid -> row=(idx)>>2, c=idx&3; LDS dest
  // = idx*16 bytes (linear, required).
  const int r0 = tid >> 2;              // 0..127
  const int c = tid & 3;
  const int stoff = tid * 8;            // f16 elems
  const int sw = (c ^ ((r0 >> 1) & 3)) * 8;   // inverse swizzle (row+128 same)

  const size_t gA0 = (size_t)(rowBase + r0) * HIDDEN + sw;
  const size_t gA1 = (size_t)(rowBase + 128 + r0) * HIDDEN + sw;
  const size_t gB0 = (size_t)(colBase + r0) * HIDDEN + sw;

  f32x4 acc[4][4];
  const f32x4 zero4 = {0.f, 0.f, 0.f, 0.f};
#pragma unroll
  for (int m = 0; m < 4; ++m)
#pragma unroll
    for (int n = 0; n < 4; ++n) acc[m][n] = zero4;

  // swizzled read offsets (row-dependent chunk XOR)
  int roffA[4], roffB[4];
#pragma unroll
  for (int m = 0; m < 4; ++m) {
    int row = wr + m * 16 + lr;
    roffA[m] = row * BK + ((kch ^ ((row >> 1) & 3)) << 3);
  }
#pragma unroll
  for (int n = 0; n < 4; ++n) {
    int row = wc + n * 16 + lr;
    roffB[n] = row * BK + ((kch ^ ((row >> 1) & 3)) << 3);
  }

#define STAGE(slot, kb)                                       \
  do {                                                        \
    f16* sA_ = smem[slot];                                    \
    f16* sB_ = smem[slot] + BM * BK;                          \
    async_copy16(xh + gA0 + (kb), sA_ + stoff);               \
    async_copy16(xh + gA1 + (kb), sA_ + stoff + 4096);        \
    async_copy16(wh + gB0 + (kb), sB_ + stoff);               \
  } while (0)

#define COMPUTE(slot)                                         \
  do {                                                        \
    const f16* sA_ = smem[slot];                              \
    const f16* sB_ = smem[slot] + BM * BK;                    \
    f16x8 a[4], b[4];                                         \
    _Pragma("unroll")                                         \
    for (int m = 0; m < 4; ++m) a[m] = *(const f16x8*)(sA_ + roffA[m]); \
    _Pragma("unroll")                                         \
    for (int n = 0; n < 4; ++n) b[n] = *(const f16x8*)(sB_ + roffB[n]); \
    _Pragma("unroll")                                         \
    for (int m = 0; m < 4; ++m)                               \
      _Pragma("unroll")                                       \
      for (int n = 0; n < 4; ++n)                             \
        acc[m][n] = __builtin_amdgcn_mfma_f32_16x16x32_f16(a[m], b[n], acc[m][n], 0, 0, 0); \
  } while (0)

  // prologue: stage tiles 0 and 1
  STAGE(0, 0);
  STAGE(1, BK);

  // main loop: stage t+2, wait own stage t landed (vmcnt(6) = two newer
  // 3-load stages outstanding), barrier aligns all waves.
  for (int t = 0; t < NT - 2; ++t) {
    STAGE((t + 2) % 3, (t + 2) * BK);
    asm volatile("s_waitcnt vmcnt(6)\n\ts_barrier" ::: "memory");
    COMPUTE(t % 3);
    asm volatile("s_barrier" ::: "memory");   // protect slot (t-1)%3 reuse
  }
  asm volatile("s_waitcnt vmcnt(3)\n\ts_barrier" ::: "memory");
  COMPUTE((NT - 2) % 3);
  asm volatile("s_barrier" ::: "memory");
  asm volatile("s_waitcnt vmcnt(0)\n\ts_barrier" ::: "memory");
  COMPUTE((NT - 1) % 3);
#undef STAGE
#undef COMPUTE

  // epilogue: bias + T0 filter + compact append
  // C/D layout (verified m89/m91): col = lane&15, row = (lane>>4)*4 + reg
  const int ccol = lane & 15;
  const int crow = (lane >> 4) * 4;
#pragma unroll
  for (int n = 0; n < 4; ++n) {
    int col = colBase + wc + n * 16 + ccol;
    float bias = b1[col];
    u32 inv = 0xFFFFFFFFu - (u32)col;
#pragma unroll
    for (int m = 0; m < 4; ++m) {
      int rowb = rowBase + wr + m * 16 + crow;
#pragma unroll
      for (int j = 0; j < 4; ++j) {
        float val = acc[m][n][j] + bias;
        if (fabsf(val) >= T0) {
          int row = rowb + j;
          int pos = atomicAdd(&cnt[row], 1);
          if (pos < CCAP) {
            ckeys[(size_t)row * CCAP + pos] =
                ((u64)__float_as_uint(fabsf(val)) << 32) | (u64)inv;
            cvals[(size_t)row * CCAP + pos] = val;
          }
        }
      }
    }
  }
}

// ------------------------------------------------- per-row select + adjudicate + gather (fused)
// Rank-select top-40, verified round-4..18 adjudication (MU-band classify,
// OpenBLAS kc=384 fp32-chain emulation, cube), index-ascending order, then
// the sparse gather from fp16 W2T.
__global__ __launch_bounds__(256)
void topk_scatter(const u64* __restrict__ ckeys, const float* __restrict__ cvals,
                  const int* __restrict__ cnt,
                  const float* __restrict__ x, const float* __restrict__ W1,
                  const float* __restrict__ b1,
                  const f16* __restrict__ w2t, const float* __restrict__ b2,
                  float* __restrict__ out) {
  const int row = blockIdx.x;
  const int tid = threadIdx.x;

  __shared__ u64 k_lds[CCAP];
  __shared__ float v_lds[CCAP];
  __shared__ float sval[NCAND];
  __shared__ int   sidx[NCAND];
  __shared__ int   sS, sB;
  __shared__ float sv32[NCAND];
  __shared__ int   fidx[TOPK_K];
  __shared__ float fcoef[TOPK_K];
  __shared__ int   sIdx[TOPK_K];     // index-ascending
  __shared__ float sCf[TOPK_K];

  int c = cnt[row];
  c = c < CCAP ? c : CCAP;
  if (tid < c) {
    k_lds[tid] = ckeys[(size_t)row * CCAP + tid];
    v_lds[tid] = cvals[(size_t)row * CCAP + tid];
  }
  if (tid < NCAND) { sval[tid] = 0.f; sidx[tid] = 0x7FFF0000 + tid; }
  __syncthreads();

  // parallel rank-select (keys unique -> strict order)
  if (tid < c) {
    const u64 mine = k_lds[tid];
    int rank = 0;
    for (int j2 = 0; j2 < c; ++j2)
      rank += (k_lds[j2] > mine) ? 1 : 0;
    if (rank < NCAND) {
      sval[rank] = v_lds[tid];
      sidx[rank] = (int)(0xFFFFFFFFu - (u32)(mine & 0xFFFFFFFFull));
    }
  }
  __syncthreads();

  // classify: sure-in prefix (> t+MU) vs boundary band [t-MU, t+MU]
  if (tid == 0) {
    float t = fabsf(sval[TOPK_K - 1]);
    int s = 0;
    while (s < TOPK_K - 1 && fabsf(sval[s]) > t + MU) ++s;
    int e = s;
    while (e < NCAND && fabsf(sval[e]) >= t - MU) ++e;
    sS = s;
    sB = e - s;       // >= 1 always (slot 31 is in the band)
  }
  __syncthreads();
  const int s = sS, nb = sB;

  // OpenBLAS-sgemm rounding emulation for boundary candidates
  if (nb > 1 && tid < nb) {
    const int fi = sidx[s + tid];
    const float* xr = x + (size_t)row * HIDDEN;
    const float* w1r = W1 + (size_t)fi * HIDDEN;
    float p0 = 0.0f, p1 = 0.0f, p2 = 0.0f;
    for (int k2 = 0; k2 < KC; ++k2)
      p0 = __builtin_fmaf(xr[k2], w1r[k2], p0);
    for (int k2 = KC; k2 < 2 * KC; ++k2)
      p1 = __builtin_fmaf(xr[k2], w1r[k2], p1);
    for (int k2 = 2 * KC; k2 < HIDDEN; ++k2)
      p2 = __builtin_fmaf(xr[k2], w1r[k2], p2);
    float acc = __fadd_rn(__fadd_rn(p0, p1), p2);   // C += panel merges
    sv32[tid] = __fadd_rn(acc, b1[fi]);
  }
  __syncthreads();

  if (tid == 0) {
    for (int k2 = 0; k2 < TOPK_K; ++k2) {
      fidx[k2] = sidx[k2];
      float hv = sval[k2];
      fcoef[k2] = __fmul_rn(__fmul_rn(hv, hv), hv);
    }
    if (nb > 1) {
      int need = TOPK_K - s;
      u64 used = 0;
      for (int n = 0; n < need; ++n) {
        int bestc = -1;
        u64 bestk = 0;
        for (int c2 = 0; c2 < nb; ++c2) {
          if (used & (1ull << c2)) continue;
          unsigned abv = __float_as_uint(fabsf(sv32[c2]));
          u64 kk2 = ((u64)abv << 32) | (u64)(0xFFFFFFFFu - (unsigned)sidx[s + c2]);
          if (bestc < 0 || kk2 > bestk) { bestk = kk2; bestc = c2; }
        }
        used |= 1ull << bestc;
        float hv = sv32[bestc];
        fidx[s + n] = sidx[s + bestc];
        fcoef[s + n] = __fmul_rn(__fmul_rn(hv, hv), hv);
      }
    }
  }
  __syncthreads();

  // index-ascending placement into LDS (indices unique -> exact permutation)
  if (tid < TOPK_K) {
    int myi = fidx[tid];
    float myc = fcoef[tid];
    int rank = 0;
#pragma unroll
    for (int j2 = 0; j2 < TOPK_K; ++j2)
      rank += (fidx[j2] < myi) ? 1 : 0;
    sIdx[rank] = myi;
    sCf[rank] = myc;
  }
  __syncthreads();

  // sparse gather from fp16 W2T: out[row][:] = sum_j coef_j * W2T[idx_j][:] + b2
  float4 acc = {0.f, 0.f, 0.f, 0.f};
  for (int j = 0; j < TOPK_K; ++j) {
    const f16x4 w = *reinterpret_cast<const f16x4*>(w2t + (size_t)sIdx[j] * HIDDEN + tid * 4);
    float cf = sCf[j];
    acc.x = __builtin_fmaf(cf, (float)w[0], acc.x);
    acc.y = __builtin_fmaf(cf, (float)w[1], acc.y);
    acc.z = __builtin_fmaf(cf, (float)w[2], acc.z);
    acc.w = __builtin_fmaf(cf, (float)w[3], acc.w);
  }
  const float4 bb = reinterpret_cast<const float4*>(b2)[tid];
  acc.x += bb.x; acc.y += bb.y; acc.z += bb.z; acc.w += bb.w;
  reinterpret_cast<float4*>(out)[(size_t)row * (HIDDEN / 4) + tid] = acc;
}

// ------------------------------------------------- launch
extern "C" void kernel_launch(void* const* d_in, const int* in_sizes, int n_in,
                              void* d_out, int out_size, void* d_ws, size_t ws_size,
                              hipStream_t stream) {
  (void)in_sizes; (void)n_in; (void)out_size; (void)ws_size;
  const float* x  = (const float*)d_in[0];
  const float* W1 = (const float*)d_in[1];
  const float* b1 = (const float*)d_in[2];
  const float* W2 = (const float*)d_in[3];
  const float* b2 = (const float*)d_in[4];
  float* out = (float*)d_out;

  // workspace layout (~59 MB total)
  f16* xh = (f16*)d_ws;                                           // 16.78 MB
  f16* wh = xh + (size_t)NROWS * HIDDEN;                          //  8.39 MB
  f16* w2t = wh + (size_t)FFN * HIDDEN;                           //  8.39 MB
  u64* ckeys = (u64*)(w2t + (size_t)FFN * HIDDEN);                // 16.78 MB
  float* cvals = (float*)(ckeys + (size_t)NROWS * CCAP);          //  8.39 MB
  int* cnt = (int*)(cvals + (size_t)NROWS * CCAP);                //  32 KB

  prep_kernel<<<6144, 256, 0, stream>>>(x, W1, W2, xh, wh, w2t, cnt);
  gemm_topk_fused<<<dim3(NROWS / BM, FFN / BN), 512, 0, stream>>>(xh, wh, b1, ckeys, cvals, cnt);
  topk_scatter<<<NROWS, 256, 0, stream>>>(ckeys, cvals, cnt, x, W1, b1, w2t, b2, out);
}

// Round 20
// 261.589 us; speedup vs baseline: 1.1384x; 1.0144x over previous
//
#include <hip/hip_runtime.h>
#include <hip/hip_bf16.h>
#include <stdint.h>

#define HIDDEN 1024
#define FFN    4096
#define NROWS  8192   // 4*2048
#define TOPK_K 32
#define NCAND  40
#define MU     3e-3f  // band >= 2.5x max fp16-approx error (1.2e-3)
#define KC     384    // OpenBLAS SGEMM_DEFAULT_Q (verified rounds 4-19)
#define CCAP   256    // candidate capacity (survivors ~125 +- 11; validated R5-R19)
#define T0     1.25f  // pre-filter threshold: 7.7 sigma below |h|_(40)

#define BM 256
#define BN 128
#define BK 32
#define NT (HIDDEN / BK)        // 32 K-tiles
#define BUFSZ ((BM + BN) * BK)  // f16 elems per ring slot (A+B) = 24 KB

typedef _Float16 f16;
typedef __attribute__((ext_vector_type(8))) _Float16 f16x8;
typedef __attribute__((ext_vector_type(4))) _Float16 f16x4;
typedef __attribute__((ext_vector_type(4))) float f32x4;
typedef unsigned long long u64;
typedef unsigned int u32;

__device__ __forceinline__ void async_copy16(const void* g, void* l) {
  __builtin_amdgcn_global_load_lds((void __attribute__((address_space(1)))*)(g),
                                   (void __attribute__((address_space(3)))*)(l),
                                   16, 0, 0);
}

// ------------------------------------------------- fused preprocessing:
// blocks [0,2048): fp32->fp16 convert of x and W1 (grid-stride) + zero cnt
// blocks [2048,6144): W2 transpose tile -> f16 [4096][1024]
__global__ void prep_kernel(const float* __restrict__ x, const float* __restrict__ W1,
                            const float* __restrict__ W2,
                            f16* __restrict__ xh, f16* __restrict__ wh,
                            f16* __restrict__ w2t, int* __restrict__ cnt) {
  const int tid = threadIdx.x;
  if (blockIdx.x < 2048) {
    if (tid < 4) cnt[blockIdx.x * 4 + tid] = 0;   // 2048*4 = 8192 entries
    const int n4x = NROWS * HIDDEN / 4;
    const int n4w = FFN * HIDDEN / 4;
    int i = blockIdx.x * 256 + tid;
    int stride = 2048 * 256;
    for (; i < n4x + n4w; i += stride) {
      const float4 v = (i < n4x) ? reinterpret_cast<const float4*>(x)[i]
                                 : reinterpret_cast<const float4*>(W1)[i - n4x];
      f16x4 o = {(f16)v.x, (f16)v.y, (f16)v.z, (f16)v.w};
      if (i < n4x) reinterpret_cast<f16x4*>(xh)[i] = o;
      else         reinterpret_cast<f16x4*>(wh)[i - n4x] = o;
    }
  } else {
    __shared__ float tile[32][33];
    const int b = blockIdx.x - 2048;
    const int bx = (b & 127) * 32;          // FFN
    const int by = (b >> 7) * 32;           // HIDDEN
    const int tx = tid & 31, ty = tid >> 5; // 32 x 8
#pragma unroll
    for (int r = 0; r < 32; r += 8)
      tile[ty + r][tx] = W2[(size_t)(by + ty + r) * FFN + bx + tx];
    __syncthreads();
#pragma unroll
    for (int r = 0; r < 32; r += 8)
      w2t[(size_t)(bx + ty + r) * HIDDEN + by + tx] = (f16)tile[tx][ty + r];
  }
}

// ------------------------------------------------- GEMM1 + fused T0 filter
// R19 structure (best measured: 133 us): 256x128 / 8 waves (64x64 per
// wave), 3-slot ring (72 KB -> 2 blocks/CU = 16 waves/CU) with counted
// s_waitcnt vmcnt(6) + raw s_barrier. Chunk-swizzle (rule #21 both-sides,
// 0 conflicts R9-R19).
__global__ __launch_bounds__(512)
void gemm_topk_fused(const f16* __restrict__ xh,
                     const f16* __restrict__ wh,
                     const float* __restrict__ b1,
                     u64* __restrict__ ckeys, float* __restrict__ cvals,
                     int* __restrict__ cnt) {
  __shared__ __align__(16) f16 smem[3][BUFSZ];   // 72 KB

  const int tid = threadIdx.x;
  const int rowBase = blockIdx.x * BM;
  const int colBase = blockIdx.y * BN;

  const int wid = tid >> 6, lane = tid & 63;
  const int wr = (wid >> 1) * 64;       // wave row offset (0..192)
  const int wc = (wid & 1) * 64;        // wave col offset (0 or 64)
  const int lr = lane & 15;
  const int kch = lane >> 4;            // k-chunk 0..3 (8 f16 each)

  const int r0 = tid >> 2;              // 0..127
  const int c = tid & 3;
  const int stoff = tid * 8;            // f16 elems
  const int sw = (c ^ ((r0 >> 1) & 3)) * 8;   // inverse swizzle (row+128 same)

  const size_t gA0 = (size_t)(rowBase + r0) * HIDDEN + sw;
  const size_t gA1 = (size_t)(rowBase + 128 + r0) * HIDDEN + sw;
  const size_t gB0 = (size_t)(colBase + r0) * HIDDEN + sw;

  f32x4 acc[4][4];
  const f32x4 zero4 = {0.f, 0.f, 0.f, 0.f};
#pragma unroll
  for (int m = 0; m < 4; ++m)
#pragma unroll
    for (int n = 0; n < 4; ++n) acc[m][n] = zero4;

  int roffA[4], roffB[4];
#pragma unroll
  for (int m = 0; m < 4; ++m) {
    int row = wr + m * 16 + lr;
    roffA[m] = row * BK + ((kch ^ ((row >> 1) & 3)) << 3);
  }
#pragma unroll
  for (int n = 0; n < 4; ++n) {
    int row = wc + n * 16 + lr;
    roffB[n] = row * BK + ((kch ^ ((row >> 1) & 3)) << 3);
  }

#define STAGE(slot, kb)                                       \
  do {                                                        \
    f16* sA_ = smem[slot];                                    \
    f16* sB_ = smem[slot] + BM * BK;                          \
    async_copy16(xh + gA0 + (kb), sA_ + stoff);               \
    async_copy16(xh + gA1 + (kb), sA_ + stoff + 4096);        \
    async_copy16(wh + gB0 + (kb), sB_ + stoff);               \
  } while (0)

#define COMPUTE(slot)                                         \
  do {                                                        \
    const f16* sA_ = smem[slot];                              \
    const f16* sB_ = smem[slot] + BM * BK;                    \
    f16x8 a[4], b[4];                                         \
    _Pragma("unroll")                                         \
    for (int m = 0; m < 4; ++m) a[m] = *(const f16x8*)(sA_ + roffA[m]); \
    _Pragma("unroll")                                         \
    for (int n = 0; n < 4; ++n) b[n] = *(const f16x8*)(sB_ + roffB[n]); \
    _Pragma("unroll")                                         \
    for (int m = 0; m < 4; ++m)                               \
      _Pragma("unroll")                                       \
      for (int n = 0; n < 4; ++n)                             \
        acc[m][n] = __builtin_amdgcn_mfma_f32_16x16x32_f16(a[m], b[n], acc[m][n], 0, 0, 0); \
  } while (0)

  STAGE(0, 0);
  STAGE(1, BK);

  for (int t = 0; t < NT - 2; ++t) {
    STAGE((t + 2) % 3, (t + 2) * BK);
    asm volatile("s_waitcnt vmcnt(6)\n\ts_barrier" ::: "memory");
    COMPUTE(t % 3);
    asm volatile("s_barrier" ::: "memory");   // protect slot (t-1)%3 reuse
  }
  asm volatile("s_waitcnt vmcnt(3)\n\ts_barrier" ::: "memory");
  COMPUTE((NT - 2) % 3);
  asm volatile("s_barrier" ::: "memory");
  asm volatile("s_waitcnt vmcnt(0)\n\ts_barrier" ::: "memory");
  COMPUTE((NT - 1) % 3);
#undef STAGE
#undef COMPUTE

  // epilogue: bias + T0 filter + compact append
  const int ccol = lane & 15;
  const int crow = (lane >> 4) * 4;
#pragma unroll
  for (int n = 0; n < 4; ++n) {
    int col = colBase + wc + n * 16 + ccol;
    float bias = b1[col];
    u32 inv = 0xFFFFFFFFu - (u32)col;
#pragma unroll
    for (int m = 0; m < 4; ++m) {
      int rowb = rowBase + wr + m * 16 + crow;
#pragma unroll
      for (int j = 0; j < 4; ++j) {
        float val = acc[m][n][j] + bias;
        if (fabsf(val) >= T0) {
          int row = rowb + j;
          int pos = atomicAdd(&cnt[row], 1);
          if (pos < CCAP) {
            ckeys[(size_t)row * CCAP + pos] =
                ((u64)__float_as_uint(fabsf(val)) << 32) | (u64)inv;
            cvals[(size_t)row * CCAP + pos] = val;
          }
        }
      }
    }
  }
}

// ------------------------------------------------- per-row select + adjudicate + gather (fused)
// Rank-select top-40, verified round-4..19 adjudication (MU-band classify,
// OpenBLAS kc=384 fp32-chain emulation, cube), then an ILP-optimized
// j-split gather: thread halves take 16 indices each with f16x8 (16B)
// loads and 8 independent accumulators -> 16 wide independent loads in
// flight per thread; halves combined via LDS.
__global__ __launch_bounds__(256)
void topk_scatter(const u64* __restrict__ ckeys, const float* __restrict__ cvals,
                  const int* __restrict__ cnt,
                  const float* __restrict__ x, const float* __restrict__ W1,
                  const float* __restrict__ b1,
                  const f16* __restrict__ w2t, const float* __restrict__ b2,
                  float* __restrict__ out) {
  const int row = blockIdx.x;
  const int tid = threadIdx.x;

  __shared__ u64 k_lds[CCAP];
  __shared__ float v_lds[CCAP];
  __shared__ float sval[NCAND];
  __shared__ int   sidx[NCAND];
  __shared__ int   sS, sB;
  __shared__ float sv32[NCAND];
  __shared__ int   fidx[TOPK_K];
  __shared__ float fcoef[TOPK_K];
  __shared__ int   sIdx[TOPK_K];
  __shared__ float sCf[TOPK_K];
  __shared__ float comb[128][8];     // 4 KB half-combine buffer

  int c = cnt[row];
  c = c < CCAP ? c : CCAP;
  if (tid < c) {
    k_lds[tid] = ckeys[(size_t)row * CCAP + tid];
    v_lds[tid] = cvals[(size_t)row * CCAP + tid];
  }
  if (tid < NCAND) { sval[tid] = 0.f; sidx[tid] = 0x7FFF0000 + tid; }
  __syncthreads();

  // parallel rank-select (keys unique -> strict order)
  if (tid < c) {
    const u64 mine = k_lds[tid];
    int rank = 0;
    for (int j2 = 0; j2 < c; ++j2)
      rank += (k_lds[j2] > mine) ? 1 : 0;
    if (rank < NCAND) {
      sval[rank] = v_lds[tid];
      sidx[rank] = (int)(0xFFFFFFFFu - (u32)(mine & 0xFFFFFFFFull));
    }
  }
  __syncthreads();

  // classify: sure-in prefix (> t+MU) vs boundary band [t-MU, t+MU]
  if (tid == 0) {
    float t = fabsf(sval[TOPK_K - 1]);
    int s = 0;
    while (s < TOPK_K - 1 && fabsf(sval[s]) > t + MU) ++s;
    int e = s;
    while (e < NCAND && fabsf(sval[e]) >= t - MU) ++e;
    sS = s;
    sB = e - s;       // >= 1 always (slot 31 is in the band)
  }
  __syncthreads();
  const int s = sS, nb = sB;

  // OpenBLAS-sgemm rounding emulation for boundary candidates
  if (nb > 1 && tid < nb) {
    const int fi = sidx[s + tid];
    const float* xr = x + (size_t)row * HIDDEN;
    const float* w1r = W1 + (size_t)fi * HIDDEN;
    float p0 = 0.0f, p1 = 0.0f, p2 = 0.0f;
    for (int k2 = 0; k2 < KC; ++k2)
      p0 = __builtin_fmaf(xr[k2], w1r[k2], p0);
    for (int k2 = KC; k2 < 2 * KC; ++k2)
      p1 = __builtin_fmaf(xr[k2], w1r[k2], p1);
    for (int k2 = 2 * KC; k2 < HIDDEN; ++k2)
      p2 = __builtin_fmaf(xr[k2], w1r[k2], p2);
    float acc = __fadd_rn(__fadd_rn(p0, p1), p2);   // C += panel merges
    sv32[tid] = __fadd_rn(acc, b1[fi]);
  }
  __syncthreads();

  if (tid == 0) {
    for (int k2 = 0; k2 < TOPK_K; ++k2) {
      fidx[k2] = sidx[k2];
      float hv = sval[k2];
      fcoef[k2] = __fmul_rn(__fmul_rn(hv, hv), hv);
    }
    if (nb > 1) {
      int need = TOPK_K - s;
      u64 used = 0;
      for (int n = 0; n < need; ++n) {
        int bestc = -1;
        u64 bestk = 0;
        for (int c2 = 0; c2 < nb; ++c2) {
          if (used & (1ull << c2)) continue;
          unsigned abv = __float_as_uint(fabsf(sv32[c2]));
          u64 kk2 = ((u64)abv << 32) | (u64)(0xFFFFFFFFu - (unsigned)sidx[s + c2]);
          if (bestc < 0 || kk2 > bestk) { bestk = kk2; bestc = c2; }
        }
        used |= 1ull << bestc;
        float hv = sv32[bestc];
        fidx[s + n] = sidx[s + bestc];
        fcoef[s + n] = __fmul_rn(__fmul_rn(hv, hv), hv);
      }
    }
  }
  __syncthreads();

  // index-ascending placement into LDS (indices unique -> exact permutation)
  if (tid < TOPK_K) {
    int myi = fidx[tid];
    float myc = fcoef[tid];
    int rank = 0;
#pragma unroll
    for (int j2 = 0; j2 < TOPK_K; ++j2)
      rank += (fidx[j2] < myi) ? 1 : 0;
    sIdx[rank] = myi;
    sCf[rank] = myc;
  }
  __syncthreads();

  // ILP gather: half = j-range (16 idx each), cid = 8-col slice.
  const int half = tid >> 7;         // 0 or 1
  const int cid = tid & 127;
  float a8[8];
#pragma unroll
  for (int e = 0; e < 8; ++e) a8[e] = 0.f;
#pragma unroll
  for (int jj = 0; jj < 16; ++jj) {
    const int j = half * 16 + jj;
    const f16x8 w = *reinterpret_cast<const f16x8*>(
        w2t + (size_t)sIdx[j] * HIDDEN + cid * 8);
    const float cf = sCf[j];
#pragma unroll
    for (int e = 0; e < 8; ++e)
      a8[e] = __builtin_fmaf(cf, (float)w[e], a8[e]);
  }
  if (half == 1) {
#pragma unroll
    for (int e = 0; e < 8; ++e) comb[cid][e] = a8[e];
  }
  __syncthreads();
  if (half == 0) {
    float4 o0, o1;
    o0.x = a8[0] + comb[cid][0] + b2[cid * 8 + 0];
    o0.y = a8[1] + comb[cid][1] + b2[cid * 8 + 1];
    o0.z = a8[2] + comb[cid][2] + b2[cid * 8 + 2];
    o0.w = a8[3] + comb[cid][3] + b2[cid * 8 + 3];
    o1.x = a8[4] + comb[cid][4] + b2[cid * 8 + 4];
    o1.y = a8[5] + comb[cid][5] + b2[cid * 8 + 5];
    o1.z = a8[6] + comb[cid][6] + b2[cid * 8 + 6];
    o1.w = a8[7] + comb[cid][7] + b2[cid * 8 + 7];
    reinterpret_cast<float4*>(out)[((size_t)row * HIDDEN + cid * 8) / 4] = o0;
    reinterpret_cast<float4*>(out)[((size_t)row * HIDDEN + cid * 8) / 4 + 1] = o1;
  }
}

// ------------------------------------------------- launch
extern "C" void kernel_launch(void* const* d_in, const int* in_sizes, int n_in,
                              void* d_out, int out_size, void* d_ws, size_t ws_size,
                              hipStream_t stream) {
  (void)in_sizes; (void)n_in; (void)out_size; (void)ws_size;
  const float* x  = (const float*)d_in[0];
  const float* W1 = (const float*)d_in[1];
  const float* b1 = (const float*)d_in[2];
  const float* W2 = (const float*)d_in[3];
  const float* b2 = (const float*)d_in[4];
  float* out = (float*)d_out;

  // workspace layout (~59 MB total)
  f16* xh = (f16*)d_ws;                                           // 16.78 MB
  f16* wh = xh + (size_t)NROWS * HIDDEN;                          //  8.39 MB
  f16* w2t = wh + (size_t)FFN * HIDDEN;                           //  8.39 MB
  u64* ckeys = (u64*)(w2t + (size_t)FFN * HIDDEN);                // 16.78 MB
  float* cvals = (float*)(ckeys + (size_t)NROWS * CCAP);          //  8.39 MB
  int* cnt = (int*)(cvals + (size_t)NROWS * CCAP);                //  32 KB

  prep_kernel<<<6144, 256, 0, stream>>>(x, W1, W2, xh, wh, w2t, cnt);
  gemm_topk_fused<<<dim3(NROWS / BM, FFN / BN), 512, 0, stream>>>(xh, wh, b1, ckeys, cvals, cnt);
  topk_scatter<<<NROWS, 256, 0, stream>>>(ckeys, cvals, cnt, x, W1, b1, w2t, b2, out);
}